// Round 9
// baseline (219.746 us; speedup 1.0000x reference)
//
#include <hip/hip_runtime.h>
#include <stdint.h>

// out[b,e] = (x_b - c_e)^T Sigma_e^{-1} (x_b - c_e);  E=32, B=8192, D=256, f32.
//  k_inv : X-slice bf16 convert + Neumann inverse Inv = I - M + M^2 - M^3
//          (M = Sigma - I), K-blocked layout [e][k>>3][n][k&7]
//  k_v   : v2[e] = 2*Inv_e c_e, s[e] = c^T Inv c
//  k_main R8: m201-style counted-vmcnt pipeline. Block = 256n x 256b x 4e,
//    8 waves (2wn x 4wb; wave 128n x 64b, acc 128 AGPR). X tile 128KB swizzled
//    LDS (staged once, read-only); Inv streamed as BK=32 16KB-contiguous chunks
//    into 2x16KB dbuf via gl2lds. Per chunk: raw s_barrier (NO drain) ->
//    2 phases {6 ds_read + 8 MFMA(setprio)} -> raw s_barrier -> stage t+2 ->
//    vmcnt(2). Loads stay in flight across barriers (T3/T4). Per-e bsum in
//    static regs; single end reduction in freed A-buf. Grid 256 = 1 blk/CU.
// R7 lesson: global->reg A duplicated ~2-4MB/CU through L1 (FETCH 73MB);
//    A-in-LDS + counted vmcnt removes both the duplication and R3's drain.

#define NE 32
#define NB 8192
#define DD 256

typedef __bf16 bf16_t;
typedef bf16_t bf16x8 __attribute__((ext_vector_type(8)));
typedef bf16_t bf16x4 __attribute__((ext_vector_type(4)));
typedef float  f32x4  __attribute__((ext_vector_type(4)));
typedef float  f32x16 __attribute__((ext_vector_type(16)));

#define LDX 264
#define LDT 264

static __device__ __forceinline__ void gl2lds16(const void* g, void* l) {
  __builtin_amdgcn_global_load_lds((__attribute__((address_space(1))) void*)(g),
                                   (__attribute__((address_space(3))) void*)(l),
                                   16, 0, 0);
}

// ---------------- k_inv : X-convert slice + fused Neumann inverse ----------------
__global__ __launch_bounds__(512, 2) void k_inv(const float* __restrict__ Sg,
                                                const float* __restrict__ x,
                                                bf16_t* __restrict__ Xbf,
                                                bf16_t* __restrict__ Invbf) {
  int ct = blockIdx.x;
  int e  = blockIdx.y;
  int tid = threadIdx.x, w = tid >> 6, l = tid & 63;
  __shared__ bf16_t Ml[256 * LDX];
  __shared__ bf16_t T2t[32 * LDT];
  const float* Se = Sg + (size_t)e * 65536;

  {
    int off = (blockIdx.x + 8 * blockIdx.y) * 8192 + tid * 16;
    f32x4 a0 = *(const f32x4*)(x + off);
    f32x4 a1 = *(const f32x4*)(x + off + 4);
    f32x4 a2 = *(const f32x4*)(x + off + 8);
    f32x4 a3 = *(const f32x4*)(x + off + 12);
    bf16x8 o0, o1;
#pragma unroll
    for (int j = 0; j < 4; ++j) {
      o0[j] = (bf16_t)a0[j]; o0[4 + j] = (bf16_t)a1[j];
      o1[j] = (bf16_t)a2[j]; o1[4 + j] = (bf16_t)a3[j];
    }
    *(bf16x8*)(Xbf + off) = o0;
    *(bf16x8*)(Xbf + off + 8) = o1;
  }

#pragma unroll
  for (int i = 0; i < 16; ++i) {
    int s = i * 512 + tid;
    int row = s >> 5, c8 = (s & 31) * 8;
    f32x4 a = *(const f32x4*)(Se + row * 256 + c8);
    f32x4 b = *(const f32x4*)(Se + row * 256 + c8 + 4);
    float v[8] = {a[0], a[1], a[2], a[3], b[0], b[1], b[2], b[3]};
    int dj = row - c8;
    if (dj >= 0 && dj < 8) v[dj] -= 1.0f;
    bf16x8 o;
#pragma unroll
    for (int j = 0; j < 8; ++j) o[j] = (bf16_t)v[j];
    *(bf16x8*)&Ml[row * LDX + c8] = o;
  }
  __syncthreads();

  int rA = w * 32 + (l & 15);
  int q8 = (l >> 4) * 8;
  int cg0 = ct * 32;

  f32x4 acc1[2][2];
#pragma unroll
  for (int i = 0; i < 2; ++i)
#pragma unroll
    for (int j = 0; j < 2; ++j) acc1[i][j] = (f32x4){0.f, 0.f, 0.f, 0.f};
#pragma unroll
  for (int kk = 0; kk < 256; kk += 32) {
    bf16x8 a0 = *(const bf16x8*)&Ml[rA * LDX + kk + q8];
    bf16x8 a1 = *(const bf16x8*)&Ml[(rA + 16) * LDX + kk + q8];
    bf16x8 b0 = *(const bf16x8*)&Ml[(cg0 + (l & 15)) * LDX + kk + q8];
    bf16x8 b1 = *(const bf16x8*)&Ml[(cg0 + 16 + (l & 15)) * LDX + kk + q8];
    acc1[0][0] = __builtin_amdgcn_mfma_f32_16x16x32_bf16(a0, b0, acc1[0][0], 0, 0, 0);
    acc1[0][1] = __builtin_amdgcn_mfma_f32_16x16x32_bf16(a0, b1, acc1[0][1], 0, 0, 0);
    acc1[1][0] = __builtin_amdgcn_mfma_f32_16x16x32_bf16(a1, b0, acc1[1][0], 0, 0, 0);
    acc1[1][1] = __builtin_amdgcn_mfma_f32_16x16x32_bf16(a1, b1, acc1[1][1], 0, 0, 0);
  }
#pragma unroll
  for (int nf = 0; nf < 2; ++nf) {
    int n0 = w * 32 + nf * 16 + (l >> 4) * 4;
#pragma unroll
    for (int cf = 0; cf < 2; ++cf) {
      int cl = cf * 16 + (l & 15), cg = cg0 + cl;
      bf16x4 mr = *(const bf16x4*)&Ml[cg * LDX + n0];
      f32x4 vv = acc1[nf][cf];
      bf16x4 o;
#pragma unroll
      for (int q = 0; q < 4; ++q) {
        float t2 = (((n0 + q) == cg) ? 1.0f : 0.0f) - (float)mr[q] + vv[q];
        o[q] = (bf16_t)t2;
      }
      *(bf16x4*)&T2t[cl * LDT + n0] = o;
    }
  }
  __syncthreads();

  f32x4 acc2[2][2];
#pragma unroll
  for (int i = 0; i < 2; ++i)
#pragma unroll
    for (int j = 0; j < 2; ++j) acc2[i][j] = (f32x4){0.f, 0.f, 0.f, 0.f};
#pragma unroll
  for (int kk = 0; kk < 256; kk += 32) {
    bf16x8 a0 = *(const bf16x8*)&Ml[rA * LDX + kk + q8];
    bf16x8 a1 = *(const bf16x8*)&Ml[(rA + 16) * LDX + kk + q8];
    bf16x8 b0 = *(const bf16x8*)&T2t[(l & 15) * LDT + kk + q8];
    bf16x8 b1 = *(const bf16x8*)&T2t[(16 + (l & 15)) * LDT + kk + q8];
    acc2[0][0] = __builtin_amdgcn_mfma_f32_16x16x32_bf16(a0, b0, acc2[0][0], 0, 0, 0);
    acc2[0][1] = __builtin_amdgcn_mfma_f32_16x16x32_bf16(a0, b1, acc2[0][1], 0, 0, 0);
    acc2[1][0] = __builtin_amdgcn_mfma_f32_16x16x32_bf16(a1, b0, acc2[1][0], 0, 0, 0);
    acc2[1][1] = __builtin_amdgcn_mfma_f32_16x16x32_bf16(a1, b1, acc2[1][1], 0, 0, 0);
  }
  bf16_t* Ce = Invbf + (size_t)e * 65536;
#pragma unroll
  for (int nf = 0; nf < 2; ++nf) {
    int n0 = w * 32 + nf * 16 + (l >> 4) * 4;
#pragma unroll
    for (int cf = 0; cf < 2; ++cf) {
      int cg = cg0 + cf * 16 + (l & 15);
#pragma unroll
      for (int q = 0; q < 4; ++q) {
        float vv = (((n0 + q) == cg) ? 1.0f : 0.0f) - acc2[nf][cf][q];
        Ce[(cg >> 3) * 2048 + (n0 + q) * 8 + (cg & 7)] = (bf16_t)vv;
      }
    }
  }
}

// ---------------- k_v ----------------
__global__ __launch_bounds__(256) void k_v(const bf16_t* __restrict__ Invbf,
                                           const float* __restrict__ Cent,
                                           float* __restrict__ v2,
                                           float* __restrict__ s_out) {
  int e = blockIdx.x, d = threadIdx.x;
  __shared__ float cl[256];
  __shared__ float ps[256];
  cl[d] = Cent[e * 256 + d];
  __syncthreads();
  const bf16_t* Ie = Invbf + (size_t)e * 65536 + d * 8;
  float acc = 0.f;
#pragma unroll
  for (int ksl = 0; ksl < 32; ++ksl) {
    bf16x8 r = *(const bf16x8*)(Ie + ksl * 2048);
#pragma unroll
    for (int j = 0; j < 8; ++j) acc += (float)r[j] * cl[ksl * 8 + j];
  }
  v2[e * 256 + d] = 2.0f * acc;
  ps[d] = cl[d] * acc;
  __syncthreads();
  for (int off = 128; off > 0; off >>= 1) {
    if (d < off) ps[d] += ps[d + off];
    __syncthreads();
  }
  if (d == 0) s_out[e] = ps[0];
}

// ---------------- k_main (R8: counted-vmcnt pipeline) ----------------
__global__ __launch_bounds__(512, 2) void k_main(const bf16_t* __restrict__ Xbf,
                                                 const bf16_t* __restrict__ Invbf,
                                                 const float* __restrict__ v2g,
                                                 const float* __restrict__ sg,
                                                 float* __restrict__ out) {
  int bid = blockIdx.x;
  int eg = bid & 7, bt = bid >> 3;   // XCD = eg: 4 Inv per XCD (L2-resident)
  int tid = threadIdx.x, w = tid >> 6, l = tid & 63;
  int lrow = l & 31, lhalf = l >> 5;
  int wn = w >> 2, wb = w & 3;

  __shared__ char lds[163840];
  char* Xb   = lds;            // 128KB X tile [256][256] swizzled ^((row&31)<<4)
  char* Abuf = lds + 131072;   // 2 x 16KB Inv chunk dbuf (+ end-of-kernel red)

  // ---- X stage (pre-swizzled source, linear LDS dest) ----
  const char* Xg = (const char*)Xbf + (size_t)bt * 131072;
#pragma unroll
  for (int j = 0; j < 16; ++j) {
    int base = w * 16384 + j * 1024;
    int row = (base >> 9) + (l >> 5);
    int inner = (l & 31) * 16;
    gl2lds16(Xg + row * 512 + (inner ^ ((row & 31) << 4)), Xb + base);
  }
  const char* Ainv = (const char*)Invbf + (size_t)eg * 524288;  // 4 e's, linear in t

#define STAGE(T)                                                       \
  do {                                                                 \
    const char* s_ = Ainv + (T) * 16384 + w * 2048 + (size_t)l * 16;   \
    char* d_ = Abuf + ((T) & 1) * 16384 + w * 2048;                    \
    gl2lds16(s_, d_);                                                  \
    gl2lds16(s_ + 1024, d_ + 1024);                                    \
  } while (0)

  STAGE(0);
  STAGE(1);
  asm volatile("s_waitcnt vmcnt(2)" ::: "memory");  // X + chunk0 retired; chunk1 flying

  float bsum[4][2] = {{0.f, 0.f}, {0.f, 0.f}, {0.f, 0.f}, {0.f, 0.f}};

#pragma unroll
  for (int ei = 0; ei < 4; ++ei) {
    f32x16 acc[4][2];
#pragma unroll
    for (int nf = 0; nf < 4; ++nf)
#pragma unroll
      for (int cf = 0; cf < 2; ++cf)
#pragma unroll
        for (int q = 0; q < 16; ++q) acc[nf][cf][q] = 0.f;

#pragma unroll
    for (int c = 0; c < 8; ++c) {
      const int t = ei * 8 + c;
      // entry barrier: buf[t&1] holds chunk t (retired by everyone's tail vmcnt)
      __builtin_amdgcn_sched_barrier(0);
      __builtin_amdgcn_s_barrier();
      __builtin_amdgcn_sched_barrier(0);

      const char* Ab = Abuf + (t & 1) * 16384 + lhalf * 4096 + (wn * 128 + lrow) * 16;
#pragma unroll
      for (int ks = 0; ks < 2; ++ks) {
        bf16x8 af[4], bfr[2];
#pragma unroll
        for (int nf = 0; nf < 4; ++nf)
          af[nf] = *(const bf16x8*)(Ab + ks * 8192 + nf * 512);
#pragma unroll
        for (int cf = 0; cf < 2; ++cf) {
          int b = wb * 64 + cf * 32 + lrow;
          int byte = (b * 512 + (t & 7) * 64 + ks * 32 + lhalf * 16) ^ ((b & 31) << 4);
          bfr[cf] = *(const bf16x8*)(Xb + byte);
        }
        __builtin_amdgcn_s_setprio(1);
#pragma unroll
        for (int nf = 0; nf < 4; ++nf)
#pragma unroll
          for (int cf = 0; cf < 2; ++cf)
            acc[nf][cf] = __builtin_amdgcn_mfma_f32_32x32x16_bf16(af[nf], bfr[cf], acc[nf][cf], 0, 0, 0);
        __builtin_amdgcn_s_setprio(0);
      }

      if (c == 7) {
        // per-e epilogue: bsum[ei] += X*(acc - v2); static indices only
#pragma unroll
        for (int nf = 0; nf < 4; ++nf)
#pragma unroll
          for (int g = 0; g < 4; ++g) {
            int n0 = wn * 128 + nf * 32 + 8 * g + 4 * lhalf;
            f32x4 vv = *(const f32x4*)(v2g + (eg * 4 + ei) * 256 + n0);
#pragma unroll
            for (int cf = 0; cf < 2; ++cf) {
              int b = wb * 64 + cf * 32 + lrow;
              int byte = (b * 512 + n0 * 2) ^ ((b & 31) << 4);
              bf16x4 xr = *(const bf16x4*)(Xb + byte);
#pragma unroll
              for (int q = 0; q < 4; ++q)
                bsum[ei][cf] += (float)xr[q] * (acc[nf][cf][g * 4 + q] - vv[q]);
            }
          }
      }

      // exit barrier: all waves done reading buf[t&1]
      __builtin_amdgcn_sched_barrier(0);
      __builtin_amdgcn_s_barrier();
      __builtin_amdgcn_sched_barrier(0);
      if (t + 2 <= 31) {
        STAGE(t + 2);
        asm volatile("s_waitcnt vmcnt(2)" ::: "memory");  // t+1 retired; t+2 flying
      } else if (t == 30) {
        asm volatile("s_waitcnt vmcnt(0)" ::: "memory");  // retire chunk 31
      }
    }
  }
#undef STAGE

  // ---- final cross-wave reduction (Abuf free: nothing staged after t=31) ----
  float* red = (float*)Abuf;  // [4 ei][2 wn][256 b] = 8KB
#pragma unroll
  for (int ei = 0; ei < 4; ++ei)
#pragma unroll
    for (int cf = 0; cf < 2; ++cf) {
      float r = bsum[ei][cf];
      r += __shfl_xor(r, 32);
      if (lhalf == 0) red[ei * 512 + wn * 256 + wb * 64 + cf * 32 + lrow] = r;
    }
  __syncthreads();
  if (tid < 256) {
    f32x4 o;
#pragma unroll
    for (int ei = 0; ei < 4; ++ei)
      o[ei] = sg[eg * 4 + ei] + red[ei * 512 + tid] + red[ei * 512 + 256 + tid];
    *(f32x4*)(out + (size_t)(bt * 256 + tid) * 32 + eg * 4) = o;
  }
}

extern "C" void kernel_launch(void* const* d_in, const int* in_sizes, int n_in,
                              void* d_out, int out_size, void* d_ws, size_t ws_size,
                              hipStream_t stream) {
  const float* x    = (const float*)d_in[0];
  const float* cent = (const float*)d_in[1];
  const float* sig  = (const float*)d_in[2];
  float* out = (float*)d_out;

  char* ws = (char*)d_ws;
  bf16_t* Xbf   = (bf16_t*)(ws);                 // 4MB
  bf16_t* Invbf = (bf16_t*)(ws + (4ull << 20));  // 4MB (K-blocked layout)
  float*  v2    = (float*)(ws + (8ull << 20));   // 32KB
  float*  sArr  = (float*)(ws + (8ull << 20) + 32768);

  k_inv <<<dim3(8, NE), dim3(512), 0, stream>>>(sig, x, Xbf, Invbf);
  k_v   <<<dim3(NE),    dim3(256), 0, stream>>>(Invbf, cent, v2, sArr);
  k_main<<<dim3(256),   dim3(512), 0, stream>>>(Xbf, Invbf, v2, sArr, out);
}

// Round 10
// 90.931 us; speedup vs baseline: 2.4166x; 2.4166x over previous
//
#include <hip/hip_runtime.h>
#include <stdint.h>

// out[b,e] = (x_b - c_e)^T Sigma_e^{-1} (x_b - c_e);  E=32, B=8192, D=256, f32.
//  k_inv : X-slice bf16 convert + Neumann inverse Inv = I - M + M^2 - M^3
//          (M = Sigma - I), K-blocked layout [e][k>>3][n][k&7]
//  k_v   : v2[e] = 2*Inv_e c_e, s[e] = c^T Inv c
//  k_main R9 = R1 structure (best, 52us) + K=64 chunks (half the barriers,
//    2x compiler pipelining window) + K-blocked conflict-free Inv chunk +
//    swizzled X tile + kh^wn SIMD-mate stagger + setprio.
//    Block: 256n x 256b x 4e, 8 waves (2wn x 4wb), wave 128n x 64b,
//    acc[8][4] f32x4 = 128 regs, (512,2) -> 256 cap, 1 blk/CU, LDS 160KB.
//    Per chunk: T14 issue loads(t+1) -> compute (2 kh phases) -> sync ->
//    ds_write(t+1) -> sync. R8 lesson: no raw-barrier/unroll monster (spilled).

#define NE 32
#define NB 8192
#define DD 256

typedef __bf16 bf16_t;
typedef bf16_t bf16x8 __attribute__((ext_vector_type(8)));
typedef bf16_t bf16x4 __attribute__((ext_vector_type(4)));
typedef float  f32x4  __attribute__((ext_vector_type(4)));

#define LDX 264
#define LDT 264

static __device__ __forceinline__ void gl2lds16(const void* g, void* l) {
  __builtin_amdgcn_global_load_lds((__attribute__((address_space(1))) void*)(g),
                                   (__attribute__((address_space(3))) void*)(l),
                                   16, 0, 0);
}

// ---------------- k_inv : X-convert slice + fused Neumann inverse ----------------
__global__ __launch_bounds__(512, 2) void k_inv(const float* __restrict__ Sg,
                                                const float* __restrict__ x,
                                                bf16_t* __restrict__ Xbf,
                                                bf16_t* __restrict__ Invbf) {
  int ct = blockIdx.x;
  int e  = blockIdx.y;
  int tid = threadIdx.x, w = tid >> 6, l = tid & 63;
  __shared__ bf16_t Ml[256 * LDX];
  __shared__ bf16_t T2t[32 * LDT];
  const float* Se = Sg + (size_t)e * 65536;

  {
    int off = (blockIdx.x + 8 * blockIdx.y) * 8192 + tid * 16;
    f32x4 a0 = *(const f32x4*)(x + off);
    f32x4 a1 = *(const f32x4*)(x + off + 4);
    f32x4 a2 = *(const f32x4*)(x + off + 8);
    f32x4 a3 = *(const f32x4*)(x + off + 12);
    bf16x8 o0, o1;
#pragma unroll
    for (int j = 0; j < 4; ++j) {
      o0[j] = (bf16_t)a0[j]; o0[4 + j] = (bf16_t)a1[j];
      o1[j] = (bf16_t)a2[j]; o1[4 + j] = (bf16_t)a3[j];
    }
    *(bf16x8*)(Xbf + off) = o0;
    *(bf16x8*)(Xbf + off + 8) = o1;
  }

#pragma unroll
  for (int i = 0; i < 16; ++i) {
    int s = i * 512 + tid;
    int row = s >> 5, c8 = (s & 31) * 8;
    f32x4 a = *(const f32x4*)(Se + row * 256 + c8);
    f32x4 b = *(const f32x4*)(Se + row * 256 + c8 + 4);
    float v[8] = {a[0], a[1], a[2], a[3], b[0], b[1], b[2], b[3]};
    int dj = row - c8;
    if (dj >= 0 && dj < 8) v[dj] -= 1.0f;
    bf16x8 o;
#pragma unroll
    for (int j = 0; j < 8; ++j) o[j] = (bf16_t)v[j];
    *(bf16x8*)&Ml[row * LDX + c8] = o;
  }
  __syncthreads();

  int rA = w * 32 + (l & 15);
  int q8 = (l >> 4) * 8;
  int cg0 = ct * 32;

  f32x4 acc1[2][2];
#pragma unroll
  for (int i = 0; i < 2; ++i)
#pragma unroll
    for (int j = 0; j < 2; ++j) acc1[i][j] = (f32x4){0.f, 0.f, 0.f, 0.f};
#pragma unroll
  for (int kk = 0; kk < 256; kk += 32) {
    bf16x8 a0 = *(const bf16x8*)&Ml[rA * LDX + kk + q8];
    bf16x8 a1 = *(const bf16x8*)&Ml[(rA + 16) * LDX + kk + q8];
    bf16x8 b0 = *(const bf16x8*)&Ml[(cg0 + (l & 15)) * LDX + kk + q8];
    bf16x8 b1 = *(const bf16x8*)&Ml[(cg0 + 16 + (l & 15)) * LDX + kk + q8];
    acc1[0][0] = __builtin_amdgcn_mfma_f32_16x16x32_bf16(a0, b0, acc1[0][0], 0, 0, 0);
    acc1[0][1] = __builtin_amdgcn_mfma_f32_16x16x32_bf16(a0, b1, acc1[0][1], 0, 0, 0);
    acc1[1][0] = __builtin_amdgcn_mfma_f32_16x16x32_bf16(a1, b0, acc1[1][0], 0, 0, 0);
    acc1[1][1] = __builtin_amdgcn_mfma_f32_16x16x32_bf16(a1, b1, acc1[1][1], 0, 0, 0);
  }
#pragma unroll
  for (int nf = 0; nf < 2; ++nf) {
    int n0 = w * 32 + nf * 16 + (l >> 4) * 4;
#pragma unroll
    for (int cf = 0; cf < 2; ++cf) {
      int cl = cf * 16 + (l & 15), cg = cg0 + cl;
      bf16x4 mr = *(const bf16x4*)&Ml[cg * LDX + n0];
      f32x4 vv = acc1[nf][cf];
      bf16x4 o;
#pragma unroll
      for (int q = 0; q < 4; ++q) {
        float t2 = (((n0 + q) == cg) ? 1.0f : 0.0f) - (float)mr[q] + vv[q];
        o[q] = (bf16_t)t2;
      }
      *(bf16x4*)&T2t[cl * LDT + n0] = o;
    }
  }
  __syncthreads();

  f32x4 acc2[2][2];
#pragma unroll
  for (int i = 0; i < 2; ++i)
#pragma unroll
    for (int j = 0; j < 2; ++j) acc2[i][j] = (f32x4){0.f, 0.f, 0.f, 0.f};
#pragma unroll
  for (int kk = 0; kk < 256; kk += 32) {
    bf16x8 a0 = *(const bf16x8*)&Ml[rA * LDX + kk + q8];
    bf16x8 a1 = *(const bf16x8*)&Ml[(rA + 16) * LDX + kk + q8];
    bf16x8 b0 = *(const bf16x8*)&T2t[(l & 15) * LDT + kk + q8];
    bf16x8 b1 = *(const bf16x8*)&T2t[(16 + (l & 15)) * LDT + kk + q8];
    acc2[0][0] = __builtin_amdgcn_mfma_f32_16x16x32_bf16(a0, b0, acc2[0][0], 0, 0, 0);
    acc2[0][1] = __builtin_amdgcn_mfma_f32_16x16x32_bf16(a0, b1, acc2[0][1], 0, 0, 0);
    acc2[1][0] = __builtin_amdgcn_mfma_f32_16x16x32_bf16(a1, b0, acc2[1][0], 0, 0, 0);
    acc2[1][1] = __builtin_amdgcn_mfma_f32_16x16x32_bf16(a1, b1, acc2[1][1], 0, 0, 0);
  }
  bf16_t* Ce = Invbf + (size_t)e * 65536;
#pragma unroll
  for (int nf = 0; nf < 2; ++nf) {
    int n0 = w * 32 + nf * 16 + (l >> 4) * 4;
#pragma unroll
    for (int cf = 0; cf < 2; ++cf) {
      int cg = cg0 + cf * 16 + (l & 15);
#pragma unroll
      for (int q = 0; q < 4; ++q) {
        float vv = (((n0 + q) == cg) ? 1.0f : 0.0f) - acc2[nf][cf][q];
        Ce[(cg >> 3) * 2048 + (n0 + q) * 8 + (cg & 7)] = (bf16_t)vv;
      }
    }
  }
}

// ---------------- k_v ----------------
__global__ __launch_bounds__(256) void k_v(const bf16_t* __restrict__ Invbf,
                                           const float* __restrict__ Cent,
                                           float* __restrict__ v2,
                                           float* __restrict__ s_out) {
  int e = blockIdx.x, d = threadIdx.x;
  __shared__ float cl[256];
  __shared__ float ps[256];
  cl[d] = Cent[e * 256 + d];
  __syncthreads();
  const bf16_t* Ie = Invbf + (size_t)e * 65536 + d * 8;
  float acc = 0.f;
#pragma unroll
  for (int ksl = 0; ksl < 32; ++ksl) {
    bf16x8 r = *(const bf16x8*)(Ie + ksl * 2048);
#pragma unroll
    for (int j = 0; j < 8; ++j) acc += (float)r[j] * cl[ksl * 8 + j];
  }
  v2[e * 256 + d] = 2.0f * acc;
  ps[d] = cl[d] * acc;
  __syncthreads();
  for (int off = 128; off > 0; off >>= 1) {
    if (d < off) ps[d] += ps[d + off];
    __syncthreads();
  }
  if (d == 0) s_out[e] = ps[0];
}

// ---------------- k_main (R9) ----------------
// grid (8 eg, 32 bt): XCD = eg. 512 thr = 8 waves (2wn x 4wb), wave 128n x 64b.
__global__ __launch_bounds__(512, 2) void k_main(const bf16_t* __restrict__ Xbf,
                                                 const bf16_t* __restrict__ Invbf,
                                                 const float* __restrict__ v2g,
                                                 const float* __restrict__ sg,
                                                 float* __restrict__ out) {
  int eg = blockIdx.x;
  int bt = blockIdx.y;
  int tid = threadIdx.x, w = tid >> 6, l = tid & 63;
  int wn = w >> 2, wb = w & 3;
  int l15 = l & 15, l4 = l >> 4;

  __shared__ char lds[163840];
  char* Xb = lds;            // 128KB X tile [256 rows][512B], swz byte^=((row&31)<<4)
  char* Ib = lds + 131072;   // 32KB Inv K=64 chunk (K-blocked, linear); red aliases

  // ---- one-time X stage via gl2lds, pre-swizzled SOURCE ----
  const char* Xg = (const char*)Xbf + (size_t)bt * 131072;
#pragma unroll
  for (int j = 0; j < 16; ++j) {
    int base = w * 16384 + j * 1024;
    int row = (base >> 9) + (l >> 5);
    int inner = (l & 31) * 16;
    gl2lds16(Xg + row * 512 + (inner ^ ((row & 31) << 4)), Xb + base);
  }

  for (int ei = 0; ei < 4; ++ei) {
    int e = eg * 4 + ei;
    const char* Ie = (const char*)Invbf + (size_t)e * 131072;  // K-blocked, 4x32KB

    // prologue: stage chunk 0 (linear 32KB copy, 64B/thread)
    {
      f32x4 n0 = *(const f32x4*)(Ie + tid * 16);
      f32x4 n1 = *(const f32x4*)(Ie + 8192 + tid * 16);
      f32x4 n2 = *(const f32x4*)(Ie + 16384 + tid * 16);
      f32x4 n3 = *(const f32x4*)(Ie + 24576 + tid * 16);
      *(f32x4*)(Ib + tid * 16) = n0;
      *(f32x4*)(Ib + 8192 + tid * 16) = n1;
      *(f32x4*)(Ib + 16384 + tid * 16) = n2;
      *(f32x4*)(Ib + 24576 + tid * 16) = n3;
    }
    __syncthreads();  // chunk 0 visible (and X gl2lds drained on ei=0)

    f32x4 acc[8][4];
#pragma unroll
    for (int nf = 0; nf < 8; ++nf)
#pragma unroll
      for (int bf = 0; bf < 4; ++bf) acc[nf][bf] = (f32x4){0.f, 0.f, 0.f, 0.f};

#pragma unroll
    for (int t = 0; t < 4; ++t) {
      // T14: issue next-chunk loads before compute (hidden under MFMAs)
      f32x4 n0, n1, n2, n3;
      if (t < 3) {
        const char* s = Ie + (t + 1) * 32768;
        n0 = *(const f32x4*)(s + tid * 16);
        n1 = *(const f32x4*)(s + 8192 + tid * 16);
        n2 = *(const f32x4*)(s + 16384 + tid * 16);
        n3 = *(const f32x4*)(s + 24576 + tid * 16);
      }
      // compute chunk t: 2 kh phases, wn-staggered order (SIMD-mates w, w+4
      // have opposite wn -> overlapping ds_read/MFMA phases)
#pragma unroll
      for (int kh = 0; kh < 2; ++kh) {
        int khe = kh ^ wn;
        const char* Ab = Ib + khe * 16384 + l4 * 4096 + (wn * 128 + l15) * 16;
        bf16x8 af[8];
#pragma unroll
        for (int nf = 0; nf < 8; ++nf)
          af[nf] = *(const bf16x8*)(Ab + nf * 256);
        bf16x8 bfr[4];
#pragma unroll
        for (int bf = 0; bf < 4; ++bf) {
          int b = wb * 64 + bf * 16 + l15;
          int byte = (b * 512 + (t * 64 + khe * 32 + l4 * 8) * 2) ^ ((b & 31) << 4);
          bfr[bf] = *(const bf16x8*)(Xb + byte);
        }
        __builtin_amdgcn_s_setprio(1);
#pragma unroll
        for (int nf = 0; nf < 8; ++nf)
#pragma unroll
          for (int bf = 0; bf < 4; ++bf)
            acc[nf][bf] = __builtin_amdgcn_mfma_f32_16x16x32_bf16(af[nf], bfr[bf], acc[nf][bf], 0, 0, 0);
        __builtin_amdgcn_s_setprio(0);
      }
      __syncthreads();  // all waves done reading chunk t
      if (t < 3) {      // write-late (loads returned during compute)
        *(f32x4*)(Ib + tid * 16) = n0;
        *(f32x4*)(Ib + 8192 + tid * 16) = n1;
        *(f32x4*)(Ib + 16384 + tid * 16) = n2;
        *(f32x4*)(Ib + 24576 + tid * 16) = n3;
        __syncthreads();
      }
    }

    // epilogue: bsum[b] = sum_n X[b,n]*(acc[n,b]-v2[n]);  Ib now free -> red
    float bsum[4] = {0.f, 0.f, 0.f, 0.f};
#pragma unroll
    for (int nf = 0; nf < 8; ++nf) {
      int n0 = wn * 128 + nf * 16 + l4 * 4;
      f32x4 vv = *(const f32x4*)(v2g + e * 256 + n0);
#pragma unroll
      for (int bf = 0; bf < 4; ++bf) {
        int b = wb * 64 + bf * 16 + l15;
        int byte = (b * 512 + n0 * 2) ^ ((b & 31) << 4);
        bf16x4 xr = *(const bf16x4*)(Xb + byte);
        f32x4 a = acc[nf][bf];
        bsum[bf] += (float)xr[0] * (a[0] - vv[0]) + (float)xr[1] * (a[1] - vv[1]) +
                    (float)xr[2] * (a[2] - vv[2]) + (float)xr[3] * (a[3] - vv[3]);
      }
    }
    float* red = (float*)Ib;  // [2 wn][256 b]
#pragma unroll
    for (int bf = 0; bf < 4; ++bf) {
      float r = bsum[bf];
      r += __shfl_xor(r, 16);
      r += __shfl_xor(r, 32);
      if (l4 == 0) red[wn * 256 + wb * 64 + bf * 16 + l] = r;
    }
    __syncthreads();
    if (tid < 256) {
      float res = sg[e] + red[tid] + red[256 + tid];
      out[(size_t)(bt * 256 + tid) * 32 + e] = res;
    }
    __syncthreads();  // protect red before next e's prologue write
  }
}

extern "C" void kernel_launch(void* const* d_in, const int* in_sizes, int n_in,
                              void* d_out, int out_size, void* d_ws, size_t ws_size,
                              hipStream_t stream) {
  const float* x    = (const float*)d_in[0];
  const float* cent = (const float*)d_in[1];
  const float* sig  = (const float*)d_in[2];
  float* out = (float*)d_out;

  char* ws = (char*)d_ws;
  bf16_t* Xbf   = (bf16_t*)(ws);                 // 4MB
  bf16_t* Invbf = (bf16_t*)(ws + (4ull << 20));  // 4MB (K-blocked layout)
  float*  v2    = (float*)(ws + (8ull << 20));   // 32KB
  float*  sArr  = (float*)(ws + (8ull << 20) + 32768);

  k_inv <<<dim3(8, NE), dim3(512), 0, stream>>>(sig, x, Xbf, Invbf);
  k_v   <<<dim3(NE),    dim3(256), 0, stream>>>(Invbf, cent, v2, sArr);
  k_main<<<dim3(8, 32), dim3(512), 0, stream>>>(Xbf, Invbf, v2, sArr, out);
}